// Round 4
// baseline (437.558 us; speedup 1.0000x reference)
//
#include <hip/hip_runtime.h>

#define B_ 8
#define T_ 4096
#define D_ 768
#define NH_ 12
#define M_ 64
#define ALPHA_ 0.1f

#define CCH 8          // chunks over T
#define CHUNK_T 512    // t per block
#define HALF_T 256

using half8 = __attribute__((ext_vector_type(8))) _Float16;
using short8 = __attribute__((ext_vector_type(8))) short;
using f32x4 = __attribute__((ext_vector_type(4))) float;

__device__ __forceinline__ unsigned int f2h2(float a, float b) {
    unsigned short ua = __builtin_bit_cast(unsigned short, (_Float16)a);
    unsigned short ub = __builtin_bit_cast(unsigned short, (_Float16)b);
    return (unsigned int)ua | ((unsigned int)ub << 16);
}
__device__ __forceinline__ float h2f(unsigned short u) {
    return (float)__builtin_bit_cast(_Float16, u);
}
__device__ __forceinline__ half8 cvt8(float4 a, float4 b) {
    half8 r;
    r[0] = (_Float16)a.x; r[1] = (_Float16)a.y;
    r[2] = (_Float16)a.z; r[3] = (_Float16)a.w;
    r[4] = (_Float16)b.x; r[5] = (_Float16)b.y;
    r[6] = (_Float16)b.z; r[7] = (_Float16)b.w;
    return r;
}

// ---------------------------------------------------------------------------
// Kernel 0: P[h,m,e] = (1/8) * sum_i proto[m, h*64+i] * W[h*64+i, e] -> fp16.
// ---------------------------------------------------------------------------
__global__ __launch_bounds__(256) void kP(const float* __restrict__ proto,
                                          const float* __restrict__ W,
                                          unsigned short* __restrict__ P16) {
    const int et = blockIdx.x;
    const int h  = blockIdx.y;
    const int tid = threadIdx.x;

    __shared__ __align__(16) float Ws[64 * 128];
    __shared__ __align__(16) float Ks[64 * 64];

#pragma unroll
    for (int j = 0; j < 8; ++j) {
        int f = tid + j * 256;
        int i = f >> 5, c4 = f & 31;
        const float4 v = *reinterpret_cast<const float4*>(
            W + (size_t)(h * 64 + i) * D_ + et * 128 + c4 * 4);
        *reinterpret_cast<float4*>(&Ws[i * 128 + c4 * 4]) = v;
    }
#pragma unroll
    for (int j = 0; j < 4; ++j) {
        int f = tid + j * 256;
        int m = f >> 4, i4 = f & 15;
        const float4 v = *reinterpret_cast<const float4*>(
            proto + (size_t)m * D_ + h * 64 + i4 * 4);
        Ks[(i4 * 4 + 0) * 64 + m] = v.x;
        Ks[(i4 * 4 + 1) * 64 + m] = v.y;
        Ks[(i4 * 4 + 2) * 64 + m] = v.z;
        Ks[(i4 * 4 + 3) * 64 + m] = v.w;
    }
    __syncthreads();

    const int m0 = (tid >> 5) * 8;
    const int e0 = (tid & 31) * 4;
    float acc[8][4];
#pragma unroll
    for (int i = 0; i < 8; ++i)
#pragma unroll
        for (int j = 0; j < 4; ++j) acc[i][j] = 0.f;

    for (int i = 0; i < 64; ++i) {
        const float4 bb = *reinterpret_cast<const float4*>(&Ws[i * 128 + e0]);
        const float4 a0 = *reinterpret_cast<const float4*>(&Ks[i * 64 + m0]);
        const float4 a1 = *reinterpret_cast<const float4*>(&Ks[i * 64 + m0 + 4]);
        const float a[8] = {a0.x, a0.y, a0.z, a0.w, a1.x, a1.y, a1.z, a1.w};
#pragma unroll
        for (int mi = 0; mi < 8; ++mi) {
            acc[mi][0] = fmaf(a[mi], bb.x, acc[mi][0]);
            acc[mi][1] = fmaf(a[mi], bb.y, acc[mi][1]);
            acc[mi][2] = fmaf(a[mi], bb.z, acc[mi][2]);
            acc[mi][3] = fmaf(a[mi], bb.w, acc[mi][3]);
        }
    }
#pragma unroll
    for (int mi = 0; mi < 8; ++mi) {
        size_t idx = (size_t)(h * 64 + m0 + mi) * D_ + et * 128 + e0;
        uint2 pk = {f2h2(acc[mi][0] * 0.125f, acc[mi][1] * 0.125f),
                    f2h2(acc[mi][2] * 0.125f, acc[mi][3] * 0.125f)};
        *reinterpret_cast<uint2*>(P16 + idx) = pk;
    }
}

// ---------------------------------------------------------------------------
// Kernel 1: per (chunk=512t, head, batch). Score GEMM reads BOTH operands
// direct global->register (A: fp32 H cvt in-reg; B: P16 fp16). Zero LDS,
// zero barriers in the K-loop. Then register softmax + two 256-t halves of
// {w-pack -> suffix scan -> partial MFMA} through LDS.
// grid 768 (b = p&7 pins batch per XCD), 256 threads, dyn LDS 52736 B.
//
// LDS: [0,33792) wT fp16[64][264] | [33792,50688) Hh fp16[32][264]
//      [50688,52736) segprod f32[64][8]
// ---------------------------------------------------------------------------
#define LDS_BYTES 52736

__global__ __launch_bounds__(256, 2) void k1(const float* __restrict__ H,
                                             const unsigned short* __restrict__ P16,
                                             float* __restrict__ chunkprod,
                                             float* __restrict__ partial) {
    const int p = blockIdx.x;
    const int b = p & 7;
    const int s = p >> 3;
    const int h = s % 12;
    const int c = s / 12;
    const int tid = threadIdx.x;
    const int wv  = tid >> 6;
    const int lane = tid & 63;
    const int l15 = lane & 15;
    const int q4  = lane >> 4;

    extern __shared__ __align__(16) unsigned char smem[];
    unsigned short* wT = (unsigned short*)(smem);
    unsigned short* Hh = (unsigned short*)(smem + 33792);
    float* segprod = (float*)(smem + 50688);

    const int t_base = c * CHUNK_T;
    const size_t Hbase = (size_t)(b * T_ + t_base) * D_;

    // per-lane operand base pointers (k-offset q4*8 folded in)
    const float* ap[8];
#pragma unroll
    for (int tt = 0; tt < 8; ++tt) {
        int row = (tt >> 2) * HALF_T + wv * 64 + (tt & 3) * 16 + l15;
        ap[tt] = H + Hbase + (size_t)row * D_ + q4 * 8;
    }
    const unsigned short* bp[4];
#pragma unroll
    for (int mt = 0; mt < 4; ++mt)
        bp[mt] = P16 + (size_t)(h * 64 + mt * 16 + l15) * D_ + q4 * 8;

    // ======== score GEMM: 512t x 64m, K=768, no LDS / no barriers ========
    f32x4 acc[8][4] = {};   // t = (tt>>2)*256 + wv*64 + (tt&3)*16 + q4*4 + rg
                            // m = mt*16 + l15
    for (int ks = 0; ks < 24; ++ks) {
        const int k0 = ks * 32;
        half8 bf[4];
#pragma unroll
        for (int mt = 0; mt < 4; ++mt)
            bf[mt] = *reinterpret_cast<const half8*>(bp[mt] + k0);
#pragma unroll
        for (int grp = 0; grp < 2; ++grp) {
            float4 ar[4][2];
#pragma unroll
            for (int i = 0; i < 4; ++i) {
                const float* src = ap[grp * 4 + i] + k0;
                ar[i][0] = *reinterpret_cast<const float4*>(src);
                ar[i][1] = *reinterpret_cast<const float4*>(src + 4);
            }
#pragma unroll
            for (int i = 0; i < 4; ++i) {
                half8 af = cvt8(ar[i][0], ar[i][1]);
#pragma unroll
                for (int mt = 0; mt < 4; ++mt)
                    acc[grp * 4 + i][mt] = __builtin_amdgcn_mfma_f32_16x16x32_f16(
                        af, bf[mt], acc[grp * 4 + i][mt], 0, 0, 0);
            }
        }
    }

    // ======== softmax over m in registers (reduce over l15) ========
#pragma unroll
    for (int tt = 0; tt < 8; ++tt)
#pragma unroll
        for (int rg = 0; rg < 4; ++rg) {
            float mx = fmaxf(fmaxf(acc[tt][0][rg], acc[tt][1][rg]),
                             fmaxf(acc[tt][2][rg], acc[tt][3][rg]));
#pragma unroll
            for (int msk = 1; msk <= 8; msk <<= 1)
                mx = fmaxf(mx, __shfl_xor(mx, msk, 64));
            float e0 = __expf(acc[tt][0][rg] - mx);
            float e1 = __expf(acc[tt][1][rg] - mx);
            float e2 = __expf(acc[tt][2][rg] - mx);
            float e3 = __expf(acc[tt][3][rg] - mx);
            float sm = (e0 + e1) + (e2 + e3);
#pragma unroll
            for (int msk = 1; msk <= 8; msk <<= 1)
                sm += __shfl_xor(sm, msk, 64);
            float inv = 1.0f / sm;
            acc[tt][0][rg] = e0 * inv;
            acc[tt][1][rg] = e1 * inv;
            acc[tt][2][rg] = e2 * inv;
            acc[tt][3][rg] = e3 * inv;
        }

    // ======== two 256-t halves: pack -> scan -> partial MFMA ========
    f32x4 pacc[4] = {};   // wave owns m[wv*16,+16), d-tiles of 16
    const int g = tid >> 6, m_s = tid & 63;

    for (int ph = 1; ph >= 0; --ph) {
        __syncthreads();   // wT free (prev half's MFMA reads done)
        // pack w -> wT[m][t-in-half] fp16, pitch 264
#pragma unroll
        for (int tt2 = 0; tt2 < 4; ++tt2) {
            const int tt = ph * 4 + tt2;
#pragma unroll
            for (int mt = 0; mt < 4; ++mt) {
                uint2 pk = {f2h2(acc[tt][mt][0], acc[tt][mt][1]),
                            f2h2(acc[tt][mt][2], acc[tt][mt][3])};
                *reinterpret_cast<uint2*>(
                    wT + (mt * 16 + l15) * 264 + wv * 64 + tt2 * 16 + q4 * 4) = pk;
            }
        }
        __syncthreads();

        // scan: 4 segments x 64 t within this half; seg_global = ph*4+g
        {
            const int seg = ph * 4 + g;
            unsigned short* rowp = wT + m_s * 264 + g * 64;
            float pband = 1.0f;
#pragma unroll
            for (int oct = 0; oct < 8; ++oct) {
                short8 v = *reinterpret_cast<const short8*>(rowp + oct * 8);
#pragma unroll
                for (int j = 0; j < 8; ++j)
                    pband *= fmaf(-ALPHA_, h2f((unsigned short)v[j]), 1.0f);
            }
            segprod[m_s * 8 + seg] = pband;
            __syncthreads();
            float R = 1.0f;
#pragma unroll
            for (int s2 = 0; s2 < 8; ++s2)
                if (s2 > seg) R *= segprod[m_s * 8 + s2];
#pragma unroll
            for (int oct = 7; oct >= 0; --oct) {
                short8 v = *reinterpret_cast<const short8*>(rowp + oct * 8);
                short8 o;
#pragma unroll
                for (int j = 7; j >= 0; --j) {
                    float w = h2f((unsigned short)v[j]);
                    _Float16 we = (_Float16)(ALPHA_ * w * R);
                    o[j] = (short)__builtin_bit_cast(unsigned short, we);
                    R *= fmaf(-ALPHA_, w, 1.0f);
                }
                *reinterpret_cast<short8*>(rowp + oct * 8) = o;
            }
        }
        __syncthreads();   // w_eff visible

        // partial GEMM over this half's 256 t
        for (int hf = 0; hf < 2; ++hf) {
            if (hf) __syncthreads();
            // stage Hh: H[ph*256 + 256t][32d] -> fp16 [d][t], pitch 264
            {
                const int dl = tid & 31, tg = tid >> 5;
                const float* src = H + Hbase + (size_t)(ph * HALF_T + tg * 32) * D_
                                   + h * 64 + hf * 32 + dl;
                unsigned short* dst = Hh + dl * 264 + tg * 32;
#pragma unroll
                for (int i = 0; i < 32; i += 2) {
                    float a  = src[(size_t)i * D_];
                    float bb = src[(size_t)(i + 1) * D_];
                    *reinterpret_cast<unsigned int*>(dst + i) = f2h2(a, bb);
                }
            }
            __syncthreads();
#pragma unroll
            for (int ks = 0; ks < 8; ++ks) {
                half8 a = *reinterpret_cast<const half8*>(
                    wT + (wv * 16 + l15) * 264 + ks * 32 + q4 * 8);
#pragma unroll
                for (int dt = 0; dt < 2; ++dt) {
                    half8 bb = *reinterpret_cast<const half8*>(
                        Hh + (dt * 16 + l15) * 264 + ks * 32 + q4 * 8);
                    pacc[hf * 2 + dt] = __builtin_amdgcn_mfma_f32_16x16x32_f16(
                        a, bb, pacc[hf * 2 + dt], 0, 0, 0);
                }
            }
        }
    }

    const int chunkIdx = (b * NH_ + h) * CCH + c;
    if (tid < 64) {
        float r = 1.0f;
#pragma unroll
        for (int s2 = 0; s2 < 8; ++s2) r *= segprod[tid * 8 + s2];
        chunkprod[(size_t)chunkIdx * 64 + tid] = r;
    }
#pragma unroll
    for (int dt = 0; dt < 4; ++dt)
#pragma unroll
        for (int rg = 0; rg < 4; ++rg)
            partial[((size_t)chunkIdx * 64 + wv * 16 + q4 * 4 + rg) * 64 + dt * 16 + l15] =
                pacc[dt][rg];
}

// ---------------------------------------------------------------------------
// Kernel 2: combine 8 chunks with cross-chunk suffix gate products + s0 term.
// ---------------------------------------------------------------------------
__global__ __launch_bounds__(256) void k2(const float* __restrict__ chunkprod,
                                          const float* __restrict__ partial,
                                          const float* __restrict__ s0,
                                          float* __restrict__ out) {
    const int h = blockIdx.x;
    const int b = blockIdx.y;
    const int tid = threadIdx.x;

    __shared__ float Sfx[CCH * M_];
    __shared__ float tot[M_];

    if (tid < M_) {
        const int m = tid;
        float run = 1.0f;
        for (int c = CCH - 1; c >= 0; --c) {
            Sfx[c * M_ + m] = run;
            run *= chunkprod[((size_t)(b * NH_ + h) * CCH + c) * M_ + m];
        }
        tot[m] = run;
    }
    __syncthreads();

    const int m  = tid >> 2;
    const int d0 = (tid & 3) * 16;
    const float tm = tot[m];
    float4 acc[4];
#pragma unroll
    for (int qq = 0; qq < 4; ++qq) {
        const float4 v = *reinterpret_cast<const float4*>(
            s0 + (size_t)m * D_ + h * 64 + d0 + qq * 4);
        acc[qq] = make_float4(v.x * tm, v.y * tm, v.z * tm, v.w * tm);
    }
    for (int c = 0; c < CCH; ++c) {
        const float sv = Sfx[c * M_ + m];
        const size_t base = (((size_t)(b * NH_ + h) * CCH + c) * M_ + m) * 64 + d0;
#pragma unroll
        for (int qq = 0; qq < 4; ++qq) {
            const float4 pp = *reinterpret_cast<const float4*>(partial + base + qq * 4);
            acc[qq].x = fmaf(sv, pp.x, acc[qq].x);
            acc[qq].y = fmaf(sv, pp.y, acc[qq].y);
            acc[qq].z = fmaf(sv, pp.z, acc[qq].z);
            acc[qq].w = fmaf(sv, pp.w, acc[qq].w);
        }
    }
    const size_t ob = (size_t)(b * M_ + m) * D_ + h * 64 + d0;
#pragma unroll
    for (int qq = 0; qq < 4; ++qq)
        *reinterpret_cast<float4*>(out + ob + qq * 4) = acc[qq];
}

// ---------------------------------------------------------------------------
extern "C" void kernel_launch(void* const* d_in, const int* in_sizes, int n_in,
                              void* d_out, int out_size, void* d_ws, size_t ws_size,
                              hipStream_t stream) {
    const float* H     = (const float*)d_in[0];
    const float* proto = (const float*)d_in[1];
    const float* W     = (const float*)d_in[2];
    const float* s0    = (const float*)d_in[3];
    float* out = (float*)d_out;

    // ws: P16 u16[589824] | chunkprod f32[49152] | partial f32[3145728]  (~14 MB)
    unsigned short* P16 = (unsigned short*)d_ws;
    float* chunkprod = (float*)((unsigned char*)d_ws + 1179648);
    float* partial   = (float*)((unsigned char*)d_ws + 1376256);

    kP<<<dim3(6, NH_), 256, 0, stream>>>(proto, W, P16);
    k1<<<dim3(768), 256, LDS_BYTES, stream>>>(H, P16, chunkprod, partial);
    k2<<<dim3(NH_, B_), 256, 0, stream>>>(chunkprod, partial, s0, out);
}

// Round 5
// 229.993 us; speedup vs baseline: 1.9025x; 1.9025x over previous
//
#include <hip/hip_runtime.h>

#define B_ 8
#define T_ 4096
#define D_ 768
#define NH_ 12
#define M_ 64
#define ALPHA_ 0.1f

#define CCH 16         // chunks over T
#define CHUNK_T 256    // t per block

using half8 = __attribute__((ext_vector_type(8))) _Float16;
using short8 = __attribute__((ext_vector_type(8))) short;
using f32x4 = __attribute__((ext_vector_type(4))) float;

__device__ __forceinline__ unsigned int f2h2(float a, float b) {
    unsigned short ua = __builtin_bit_cast(unsigned short, (_Float16)a);
    unsigned short ub = __builtin_bit_cast(unsigned short, (_Float16)b);
    return (unsigned int)ua | ((unsigned int)ub << 16);
}
__device__ __forceinline__ float h2f(unsigned short u) {
    return (float)__builtin_bit_cast(_Float16, u);
}
// async global->LDS, 16 B per lane; LDS dst must be wave-uniform base + lane*16
__device__ __forceinline__ void gload_lds16(const void* g, void* l) {
    __builtin_amdgcn_global_load_lds(
        (const __attribute__((address_space(1))) unsigned int*)g,
        (__attribute__((address_space(3))) unsigned int*)l, 16, 0, 0);
}

// ---------------------------------------------------------------------------
// Kernel H16: H fp32 -> fp16, elementwise (25.2M elems). grid 6144 x 256.
// ---------------------------------------------------------------------------
__global__ __launch_bounds__(256) void kH16(const float* __restrict__ H,
                                            unsigned short* __restrict__ H16) {
    const int i = blockIdx.x * 256 + threadIdx.x;
#pragma unroll
    for (int j = 0; j < 4; ++j) {
        const int idx = i + j * 1572864;
        const float4 v = reinterpret_cast<const float4*>(H)[idx];
        uint2 pk = {f2h2(v.x, v.y), f2h2(v.z, v.w)};
        reinterpret_cast<uint2*>(H16)[idx] = pk;
    }
}

// ---------------------------------------------------------------------------
// Kernel 0: P[h,m,e] = (1/8) * sum_i proto[m, h*64+i] * W[h*64+i, e] -> fp16.
// ---------------------------------------------------------------------------
__global__ __launch_bounds__(256) void kP(const float* __restrict__ proto,
                                          const float* __restrict__ W,
                                          unsigned short* __restrict__ P16) {
    const int et = blockIdx.x;
    const int h  = blockIdx.y;
    const int tid = threadIdx.x;

    __shared__ __align__(16) float Ws[64 * 128];
    __shared__ __align__(16) float Ks[64 * 64];

#pragma unroll
    for (int j = 0; j < 8; ++j) {
        int f = tid + j * 256;
        int i = f >> 5, c4 = f & 31;
        const float4 v = *reinterpret_cast<const float4*>(
            W + (size_t)(h * 64 + i) * D_ + et * 128 + c4 * 4);
        *reinterpret_cast<float4*>(&Ws[i * 128 + c4 * 4]) = v;
    }
#pragma unroll
    for (int j = 0; j < 4; ++j) {
        int f = tid + j * 256;
        int m = f >> 4, i4 = f & 15;
        const float4 v = *reinterpret_cast<const float4*>(
            proto + (size_t)m * D_ + h * 64 + i4 * 4);
        Ks[(i4 * 4 + 0) * 64 + m] = v.x;
        Ks[(i4 * 4 + 1) * 64 + m] = v.y;
        Ks[(i4 * 4 + 2) * 64 + m] = v.z;
        Ks[(i4 * 4 + 3) * 64 + m] = v.w;
    }
    __syncthreads();

    const int m0 = (tid >> 5) * 8;
    const int e0 = (tid & 31) * 4;
    float acc[8][4];
#pragma unroll
    for (int i = 0; i < 8; ++i)
#pragma unroll
        for (int j = 0; j < 4; ++j) acc[i][j] = 0.f;

    for (int i = 0; i < 64; ++i) {
        const float4 bb = *reinterpret_cast<const float4*>(&Ws[i * 128 + e0]);
        const float4 a0 = *reinterpret_cast<const float4*>(&Ks[i * 64 + m0]);
        const float4 a1 = *reinterpret_cast<const float4*>(&Ks[i * 64 + m0 + 4]);
        const float a[8] = {a0.x, a0.y, a0.z, a0.w, a1.x, a1.y, a1.z, a1.w};
#pragma unroll
        for (int mi = 0; mi < 8; ++mi) {
            acc[mi][0] = fmaf(a[mi], bb.x, acc[mi][0]);
            acc[mi][1] = fmaf(a[mi], bb.y, acc[mi][1]);
            acc[mi][2] = fmaf(a[mi], bb.z, acc[mi][2]);
            acc[mi][3] = fmaf(a[mi], bb.w, acc[mi][3]);
        }
    }
#pragma unroll
    for (int mi = 0; mi < 8; ++mi) {
        size_t idx = (size_t)(h * 64 + m0 + mi) * D_ + et * 128 + e0;
        uint2 pk = {f2h2(acc[mi][0] * 0.125f, acc[mi][1] * 0.125f),
                    f2h2(acc[mi][2] * 0.125f, acc[mi][3] * 0.125f)};
        *reinterpret_cast<uint2*>(P16 + idx) = pk;
    }
}

// ---------------------------------------------------------------------------
// Kernel 1: per (chunk=256t, head, batch). Score GEMM stages A (H16) and B
// (P16) via global_load_lds w=16 with granule XOR-swizzle (g' = g ^ (row&7))
// so frag ds_read_b128 is conflict-free despite the lane-linear DMA layout.
// Then register softmax + segmented suffix scan + fp16 MFMA partial.
// grid 1536 (b = p&7 pins batch per XCD), 256 threads, dyn LDS 51712 B.
//
// LDS (bytes): [0,32768) A fp16[256 t][64 k] swizzled | [32768,40960) B [64 m][64 k]
//   alias: [0,33792) wT fp16[64 m][264 t] | [33792,50688) Hh fp16[32 d][264 t]
//   [50688,51712) segprod f32[64][4]
// ---------------------------------------------------------------------------
#define LDS_BYTES 51712

__global__ __launch_bounds__(256, 3) void k1(const unsigned short* __restrict__ H16,
                                             const unsigned short* __restrict__ P16,
                                             float* __restrict__ chunkprod,
                                             float* __restrict__ partial) {
    const int p = blockIdx.x;
    const int b = p & 7;
    const int s = p >> 3;
    const int h = s % 12;
    const int c = s / 12;
    const int tid = threadIdx.x;
    const int wv  = tid >> 6;
    const int lane = tid & 63;
    const int l15 = lane & 15;
    const int q4  = lane >> 4;

    extern __shared__ __align__(16) unsigned char smem[];
    unsigned short* wT = (unsigned short*)(smem);
    unsigned short* Hh = (unsigned short*)(smem + 33792);
    float* segprod = (float*)(smem + 50688);

    const size_t Hrow = (size_t)(b * T_ + c * CHUNK_T);
    const unsigned short* gA = H16 + Hrow * D_;
    const unsigned short* gB = P16 + (size_t)h * 64 * D_;

    // ======== score GEMM: 256t x 64m, K=768, fp16, DMA-staged ========
    f32x4 acc[4][4] = {};   // t = tt*16+q4*4+rg (row), m = mt*16+l15 (col), wave owns t[wv*64,+64)

    for (int kt = 0; kt < 12; ++kt) {
        __syncthreads();
        // A: 2048 granules of 16 B; slot s -> row r=s>>3, lds-granule gp=s&7,
        // fetched data granule g = gp ^ (r&7)
#pragma unroll
        for (int j = 0; j < 8; ++j) {
            int sl = j * 256 + tid;
            int r = sl >> 3, gp = sl & 7, g = gp ^ (r & 7);
            gload_lds16(gA + (size_t)r * D_ + kt * 64 + g * 8, smem + sl * 16);
        }
        // B: 512 granules
#pragma unroll
        for (int j = 0; j < 2; ++j) {
            int sl = j * 256 + tid;
            int r = sl >> 3, gp = sl & 7, g = gp ^ (r & 7);
            gload_lds16(gB + (size_t)r * D_ + kt * 64 + g * 8, smem + 32768 + sl * 16);
        }
        __syncthreads();
#pragma unroll
        for (int ks = 0; ks < 2; ++ks) {
            const int gp = ((ks * 4 + q4) ^ (l15 & 7)) * 16;
            half8 af[4], bf[4];
#pragma unroll
            for (int tt = 0; tt < 4; ++tt)
                af[tt] = *reinterpret_cast<const half8*>(
                    smem + (wv * 64 + tt * 16 + l15) * 128 + gp);
#pragma unroll
            for (int mt = 0; mt < 4; ++mt)
                bf[mt] = *reinterpret_cast<const half8*>(
                    smem + 32768 + (mt * 16 + l15) * 128 + gp);
#pragma unroll
            for (int tt = 0; tt < 4; ++tt)
#pragma unroll
                for (int mt = 0; mt < 4; ++mt)
                    acc[tt][mt] = __builtin_amdgcn_mfma_f32_16x16x32_f16(
                        af[tt], bf[mt], acc[tt][mt], 0, 0, 0);
        }
    }
    __syncthreads();   // frag reads done; wT aliases A/B

    // ======== softmax over m in registers (reduce over l15) ========
#pragma unroll
    for (int tt = 0; tt < 4; ++tt)
#pragma unroll
        for (int rg = 0; rg < 4; ++rg) {
            float mx = fmaxf(fmaxf(acc[tt][0][rg], acc[tt][1][rg]),
                             fmaxf(acc[tt][2][rg], acc[tt][3][rg]));
#pragma unroll
            for (int msk = 1; msk <= 8; msk <<= 1)
                mx = fmaxf(mx, __shfl_xor(mx, msk, 64));
            float e0 = __expf(acc[tt][0][rg] - mx);
            float e1 = __expf(acc[tt][1][rg] - mx);
            float e2 = __expf(acc[tt][2][rg] - mx);
            float e3 = __expf(acc[tt][3][rg] - mx);
            float sm = (e0 + e1) + (e2 + e3);
#pragma unroll
            for (int msk = 1; msk <= 8; msk <<= 1)
                sm += __shfl_xor(sm, msk, 64);
            float inv = 1.0f / sm;
            acc[tt][0][rg] = e0 * inv;
            acc[tt][1][rg] = e1 * inv;
            acc[tt][2][rg] = e2 * inv;
            acc[tt][3][rg] = e3 * inv;
        }
    // pack w -> wT[m][t] fp16, pitch 264
#pragma unroll
    for (int tt = 0; tt < 4; ++tt)
#pragma unroll
        for (int mt = 0; mt < 4; ++mt) {
            uint2 pk = {f2h2(acc[tt][mt][0], acc[tt][mt][1]),
                        f2h2(acc[tt][mt][2], acc[tt][mt][3])};
            *reinterpret_cast<uint2*>(
                wT + (mt * 16 + l15) * 264 + wv * 64 + tt * 16 + q4 * 4) = pk;
        }
    __syncthreads();

    // ======== segmented suffix gate scan (4 segments x 64 t) ========
    {
        const int g = tid >> 6, m_s = tid & 63;
        unsigned short* rowp = wT + m_s * 264 + g * 64;
        float pband = 1.0f;
#pragma unroll
        for (int oct = 0; oct < 8; ++oct) {
            short8 v = *reinterpret_cast<const short8*>(rowp + oct * 8);
#pragma unroll
            for (int j = 0; j < 8; ++j)
                pband *= fmaf(-ALPHA_, h2f((unsigned short)v[j]), 1.0f);
        }
        segprod[m_s * 4 + g] = pband;
        __syncthreads();
        float R = 1.0f;
#pragma unroll
        for (int gg = 1; gg < 4; ++gg)
            if (g + gg < 4) R *= segprod[m_s * 4 + g + gg];
#pragma unroll
        for (int oct = 7; oct >= 0; --oct) {
            short8 v = *reinterpret_cast<const short8*>(rowp + oct * 8);
            short8 o;
#pragma unroll
            for (int j = 7; j >= 0; --j) {
                float w = h2f((unsigned short)v[j]);
                _Float16 we = (_Float16)(ALPHA_ * w * R);
                o[j] = (short)__builtin_bit_cast(unsigned short, we);
                R *= fmaf(-ALPHA_, w, 1.0f);
            }
            *reinterpret_cast<short8*>(rowp + oct * 8) = o;
        }
    }
    __syncthreads();   // w_eff visible

    // ======== partial GEMM: pacc[m][d] += w_eff^T . H_head (fp16) ========
    f32x4 pacc[4] = {};   // wave owns m[wv*16,+16), 4 d-tiles of 16
    for (int hf = 0; hf < 2; ++hf) {
        if (hf) __syncthreads();
        // stage Hh: H16[256 t][32 d] -> [d][t], pitch 264
        {
            const int dp = tid & 15, tg = tid >> 4;
            const unsigned short* src = H16 + (Hrow + tg * 16) * D_
                                        + h * 64 + hf * 32 + 2 * dp;
            unsigned short* dst0 = Hh + (2 * dp) * 264 + tg * 16;
            unsigned short* dst1 = Hh + (2 * dp + 1) * 264 + tg * 16;
#pragma unroll
            for (int i = 0; i < 16; ++i) {
                unsigned int v = *reinterpret_cast<const unsigned int*>(src + (size_t)i * D_);
                dst0[i] = (unsigned short)(v & 0xffffu);
                dst1[i] = (unsigned short)(v >> 16);
            }
        }
        __syncthreads();
#pragma unroll
        for (int ks = 0; ks < 8; ++ks) {
            half8 a = *reinterpret_cast<const half8*>(
                wT + (wv * 16 + l15) * 264 + ks * 32 + q4 * 8);
#pragma unroll
            for (int dt = 0; dt < 2; ++dt) {
                half8 bb = *reinterpret_cast<const half8*>(
                    Hh + (dt * 16 + l15) * 264 + ks * 32 + q4 * 8);
                pacc[hf * 2 + dt] = __builtin_amdgcn_mfma_f32_16x16x32_f16(
                    a, bb, pacc[hf * 2 + dt], 0, 0, 0);
            }
        }
    }

    const int chunkIdx = (b * NH_ + h) * CCH + c;
    if (tid < 64)
        chunkprod[(size_t)chunkIdx * 64 + tid] =
            (segprod[tid * 4 + 0] * segprod[tid * 4 + 1]) *
            (segprod[tid * 4 + 2] * segprod[tid * 4 + 3]);
#pragma unroll
    for (int dt = 0; dt < 4; ++dt)
#pragma unroll
        for (int rg = 0; rg < 4; ++rg)
            partial[((size_t)chunkIdx * 64 + wv * 16 + q4 * 4 + rg) * 64 + dt * 16 + l15] =
                pacc[dt][rg];
}

// ---------------------------------------------------------------------------
// Kernel 2: combine 16 chunks; grid (12, 8, 4) — mg picks 16 m-rows.
// ---------------------------------------------------------------------------
__global__ __launch_bounds__(256) void k2(const float* __restrict__ chunkprod,
                                          const float* __restrict__ partial,
                                          const float* __restrict__ s0,
                                          float* __restrict__ out) {
    const int h = blockIdx.x;
    const int b = blockIdx.y;
    const int mg = blockIdx.z;
    const int tid = threadIdx.x;
    const int m  = mg * 16 + (tid >> 4);
    const int d0 = (tid & 15) * 4;

    const size_t cpBase = (size_t)(b * NH_ + h) * CCH;
    float sfx[CCH];
    float run = 1.0f;
#pragma unroll
    for (int c = CCH - 1; c >= 0; --c) {
        sfx[c] = run;
        run *= chunkprod[(cpBase + c) * M_ + m];
    }
    const float4 v0 = *reinterpret_cast<const float4*>(
        s0 + (size_t)m * D_ + h * 64 + d0);
    float4 acc = make_float4(v0.x * run, v0.y * run, v0.z * run, v0.w * run);
#pragma unroll
    for (int c = 0; c < CCH; ++c) {
        const float sv = sfx[c];
        const float4 pp = *reinterpret_cast<const float4*>(
            partial + ((cpBase + c) * M_ + m) * 64 + d0);
        acc.x = fmaf(sv, pp.x, acc.x);
        acc.y = fmaf(sv, pp.y, acc.y);
        acc.z = fmaf(sv, pp.z, acc.z);
        acc.w = fmaf(sv, pp.w, acc.w);
    }
    *reinterpret_cast<float4*>(out + (size_t)(b * M_ + m) * D_ + h * 64 + d0) = acc;
}

// ---------------------------------------------------------------------------
extern "C" void kernel_launch(void* const* d_in, const int* in_sizes, int n_in,
                              void* d_out, int out_size, void* d_ws, size_t ws_size,
                              hipStream_t stream) {
    const float* H     = (const float*)d_in[0];
    const float* proto = (const float*)d_in[1];
    const float* W     = (const float*)d_in[2];
    const float* s0    = (const float*)d_in[3];
    float* out = (float*)d_out;

    // ws: H16 u16[25165824] (50.3 MB) | P16 u16[589824] (1.18 MB)
    //     | chunkprod f32[98304] | partial f32[6291456] (25.2 MB)   ~77 MB
    unsigned short* H16 = (unsigned short*)d_ws;
    unsigned short* P16 = (unsigned short*)((unsigned char*)d_ws + 50331648);
    float* chunkprod = (float*)((unsigned char*)d_ws + 51511296);
    float* partial   = (float*)((unsigned char*)d_ws + 51904512);

    kH16<<<dim3(6144), 256, 0, stream>>>(H, H16);
    kP<<<dim3(6, NH_), 256, 0, stream>>>(proto, W, P16);
    k1<<<dim3(1536), 256, LDS_BYTES, stream>>>(H16, P16, chunkprod, partial);
    k2<<<dim3(NH_, B_, 4), 256, 0, stream>>>(chunkprod, partial, s0, out);
}